// Round 1
// baseline (266.404 us; speedup 1.0000x reference)
//
#include <hip/hip_runtime.h>

// ---------------- types & helpers ----------------
typedef __attribute__((ext_vector_type(8))) short short8;
typedef __attribute__((ext_vector_type(4))) float f32x4;

#define NWIN 256      // number of windows
#define NW   256      // tokens per window
#define CH   256      // channels
#define NH   8
#define DH   32
#define QKV_LD 768
#define ATTN_SCALE 0.17677669529663687f

__device__ __forceinline__ unsigned short f2bf(float f) {
  union { float f; unsigned u; } v; v.f = f;
  unsigned r = v.u + 0x7FFFu + ((v.u >> 16) & 1u);   // round-to-nearest-even
  return (unsigned short)(r >> 16);
}
__device__ __forceinline__ float bf2f(unsigned short h) {
  union { unsigned u; float f; } v; v.u = ((unsigned)h) << 16;
  return v.f;
}
// XOR swizzle: 128-byte rows (8 x 16B slots) -- T2 pattern
__device__ __forceinline__ int swz128(int row, int kb) { return row * 128 + (kb ^ ((row & 7) << 4)); }
// XOR swizzle: 512-byte rows
__device__ __forceinline__ int swz512(int row, int kb) { return row * 512 + (kb ^ ((row & 7) << 4)); }

// ---------------- weight prep: transpose + hi/lo bf16 split ----------------
__global__ __launch_bounds__(256) void k_prepw(const float* __restrict__ wqkv,
                                               const float* __restrict__ wout,
                                               unsigned short* __restrict__ wqh,
                                               unsigned short* __restrict__ wql,
                                               unsigned short* __restrict__ woh,
                                               unsigned short* __restrict__ wol) {
  int idx = blockIdx.x * 256 + threadIdx.x;       // 0..196607
  {
    // w_qkv: [256 k][768 n] -> T[n][k]
    int k = idx / 768, n = idx % 768;
    float v = wqkv[idx];
    unsigned short hi = f2bf(v);
    wqh[n * 256 + k] = hi;
    wql[n * 256 + k] = f2bf(v - bf2f(hi));
  }
  if (idx < 65536) {
    // w_out: [256 k][256 n] -> T[n][k]
    int k = idx >> 8, n = idx & 255;
    float v = wout[idx];
    unsigned short hi = f2bf(v);
    woh[n * 256 + k] = hi;
    wol[n * 256 + k] = f2bf(v - bf2f(hi));
  }
}

// ---------------- bias prep: bias8[h][q][k] = table[rel[q][k]][h] ----------------
__global__ __launch_bounds__(256) void k_prepbias(const float* __restrict__ table,
                                                  const int* __restrict__ relidx,
                                                  float* __restrict__ bias8) {
  int idx = blockIdx.x * 256 + threadIdx.x;       // 0..524287
  int h = idx >> 16;
  int qk = idx & 65535;
  bias8[idx] = table[relidx[qk] * 8 + h];
}

// ---------------- LN + window gather: x (C,D,H,W) f32 -> xn [win][tok][c] bf16 ----------------
__global__ __launch_bounds__(256) void k_ln(const float* __restrict__ x,
                                            const float* __restrict__ gamma,
                                            const float* __restrict__ beta,
                                            unsigned short* __restrict__ xn) {
  __shared__ unsigned short buf[256][66];   // [c][w], pad 66 to kill bank conflicts
  __shared__ float stats[2][4][64];
  int bid = blockIdx.x;                     // one (d,h) row: 64 w positions
  int d = bid >> 6, h = bid & 63;
  int t = threadIdx.x;
  int w = t & 63, cq = t >> 6;
  const float* xrow = x + (size_t)d * 4096 + (size_t)h * 64;
  float s0 = 0.f, s1 = 0.f;
  for (int ci = 0; ci < 64; ++ci) {
    int c = ci * 4 + cq;
    float v = xrow[(size_t)c * 65536 + w];  // coalesced across lanes (w)
    buf[c][w] = f2bf(v);
    s0 += v; s1 += v * v;
  }
  stats[0][cq][w] = s0; stats[1][cq][w] = s1;
  __syncthreads();
  int lane = t & 63, wv = t >> 6;
  int winb = (d >> 2) * 64 + (h >> 3) * 8;
  int tokb = (d & 3) * 64 + (h & 7) * 8;
  for (int wi = 0; wi < 16; ++wi) {
    int w2 = wi * 4 + wv;
    float sum = stats[0][0][w2] + stats[0][1][w2] + stats[0][2][w2] + stats[0][3][w2];
    float sq  = stats[1][0][w2] + stats[1][1][w2] + stats[1][2][w2] + stats[1][3][w2];
    float mu = sum * 0.00390625f;
    float var = sq * 0.00390625f - mu * mu;
    float rstd = rsqrtf(var + 1e-5f);
    int win = winb + (w2 >> 3);
    int tok = tokb + (w2 & 7);
    unsigned short* dst = xn + ((size_t)win * NW + tok) * CH;
    for (int cc = 0; cc < 4; ++cc) {
      int c = cc * 64 + lane;
      float v = bf2f(buf[c][w2]);
      dst[c] = f2bf((v - mu) * rstd * gamma[c] + beta[c]);  // 128B contiguous per wave
    }
  }
}

// ---------------- QKV GEMM: xn[65536][256] @ (Whi+Wlo)[256][768] -> qkv bf16 ----------------
// 128x128 tile, BK=64, 4 waves (2x2), per-wave 64x64 = 4x4 fragments.
__global__ __launch_bounds__(256) void k_qkv(const unsigned short* __restrict__ xn,
                                             const unsigned short* __restrict__ bhi,
                                             const unsigned short* __restrict__ blo,
                                             unsigned short* __restrict__ qkv) {
  __shared__ unsigned short sA[8192], sBh[8192], sBl[8192];
  int t = threadIdx.x;
  int mbase = blockIdx.x << 7, nbase = blockIdx.y << 7;
  int wid = t >> 6, lane = t & 63;
  int wm = wid >> 1, wn = wid & 1;
  f32x4 acc[4][4];
#pragma unroll
  for (int i = 0; i < 4; ++i)
#pragma unroll
    for (int j = 0; j < 4; ++j) acc[i][j] = (f32x4)(0.f);
  for (int kt = 0; kt < 4; ++kt) {
#pragma unroll
    for (int i = 0; i < 4; ++i) {
      int ch = t + (i << 8);
      int row = ch >> 3, c16 = ch & 7;            // 128 rows x 8 chunks of 16B
      size_t go = (size_t)(mbase + row) * 256 + (kt << 6) + (c16 << 3);
      short8 va = *(const short8*)(xn + go);
      *(short8*)((char*)sA + swz128(row, c16 << 4)) = va;
      size_t gb = (size_t)(nbase + row) * 256 + (kt << 6) + (c16 << 3);
      short8 vh = *(const short8*)(bhi + gb);
      *(short8*)((char*)sBh + swz128(row, c16 << 4)) = vh;
      short8 vl = *(const short8*)(blo + gb);
      *(short8*)((char*)sBl + swz128(row, c16 << 4)) = vl;
    }
    __syncthreads();
#pragma unroll
    for (int kk = 0; kk < 2; ++kk) {
      int kb = (kk << 6) + ((lane >> 4) << 4);
      short8 a[4], bh[4], bl[4];
#pragma unroll
      for (int mi = 0; mi < 4; ++mi) {
        int row = (wm << 6) + (mi << 4) + (lane & 15);
        a[mi] = *(const short8*)((char*)sA + swz128(row, kb));
      }
#pragma unroll
      for (int ni = 0; ni < 4; ++ni) {
        int row = (wn << 6) + (ni << 4) + (lane & 15);
        bh[ni] = *(const short8*)((char*)sBh + swz128(row, kb));
        bl[ni] = *(const short8*)((char*)sBl + swz128(row, kb));
      }
#pragma unroll
      for (int mi = 0; mi < 4; ++mi)
#pragma unroll
        for (int ni = 0; ni < 4; ++ni) {
          acc[mi][ni] = __builtin_amdgcn_mfma_f32_16x16x32_bf16(a[mi], bh[ni], acc[mi][ni], 0, 0, 0);
          acc[mi][ni] = __builtin_amdgcn_mfma_f32_16x16x32_bf16(a[mi], bl[ni], acc[mi][ni], 0, 0, 0);
        }
    }
    __syncthreads();
  }
#pragma unroll
  for (int mi = 0; mi < 4; ++mi)
#pragma unroll
    for (int ni = 0; ni < 4; ++ni)
#pragma unroll
      for (int r = 0; r < 4; ++r) {
        int m = mbase + (wm << 6) + (mi << 4) + ((lane >> 4) << 2) + r;
        int n = nbase + (wn << 6) + (ni << 4) + (lane & 15);
        qkv[(size_t)m * QKV_LD + n] = f2bf(acc[mi][ni][r]);
      }
}

// ---------------- attention: per (q-chunk 64, head, window) ----------------
// Q/K LDS rows padded to 80B (conflict-free b128 reads); V transposed + P use 512B swizzled rows.
__global__ __launch_bounds__(256) void k_attn(const unsigned short* __restrict__ qkv,
                                              const float* __restrict__ bias8,
                                              unsigned short* __restrict__ attnout) {
  __shared__ unsigned short Vt[8192];    // [32 dh][256 tok] swizzled (512B rows)
  __shared__ unsigned short PKQ[16384];  // phase 1: Q[64][40] + K[256][40]; phase 2: P[64][256] swizzled
  unsigned short* Qs = PKQ;              // 64*40 = 2560
  unsigned short* Ks = PKQ + 2560;       // 256*40 = 10240
  int qc = blockIdx.x, head = blockIdx.y, win = blockIdx.z;
  int t = threadIdx.x;
  int wid = t >> 6, lane = t & 63;
  const unsigned short* base = qkv + (size_t)win * NW * QKV_LD;
  { // stage Q: 64 rows x 4 x 16B
    int row = t >> 2, c8 = t & 3;
    short8 v = *(const short8*)(base + (size_t)(qc * 64 + row) * QKV_LD + head * DH + c8 * 8);
    *(short8*)(Qs + row * 40 + c8 * 8) = v;
  }
#pragma unroll
  for (int i = 0; i < 4; ++i) { // stage K: 256 rows x 4 x 16B
    int ch = t + (i << 8);
    int row = ch >> 2, c8 = ch & 3;
    short8 v = *(const short8*)(base + (size_t)row * QKV_LD + CH + head * DH + c8 * 8);
    *(short8*)(Ks + row * 40 + c8 * 8) = v;
  }
#pragma unroll
  for (int i = 0; i < 4; ++i) { // stage V transposed
    int ch = t + (i << 8);
    int row = ch >> 2, c8 = ch & 3;
    short8 v = *(const short8*)(base + (size_t)row * QKV_LD + 2 * CH + head * DH + c8 * 8);
#pragma unroll
    for (int j = 0; j < 8; ++j) {
      int dh = c8 * 8 + j;
      *(unsigned short*)((char*)Vt + swz512(dh, row * 2)) = (unsigned short)v[j];
    }
  }
  __syncthreads();
  // ---- scores = Q K^T (per wave: 16 q-rows x 256 tokens) ----
  short8 aq;
  { int row = (wid << 4) + (lane & 15);
    aq = *(const short8*)(Qs + row * 40 + ((lane >> 4) << 3)); }
  f32x4 zero = (f32x4)(0.f);
  f32x4 sc[16];
#pragma unroll
  for (int nt = 0; nt < 16; ++nt) {
    int row = (nt << 4) + (lane & 15);
    short8 b = *(const short8*)(Ks + row * 40 + ((lane >> 4) << 3));
    sc[nt] = __builtin_amdgcn_mfma_f32_16x16x32_bf16(aq, b, zero, 0, 0, 0);
  }
  // ---- bias + scale + wave-parallel softmax (16-lane groups) ----
  const float* brow = bias8 + (size_t)head * 65536 + (size_t)(qc * 64 + (wid << 4)) * 256;
  float m[4] = {-1e30f, -1e30f, -1e30f, -1e30f};
#pragma unroll
  for (int nt = 0; nt < 16; ++nt)
#pragma unroll
    for (int r = 0; r < 4; ++r) {
      int ql = ((lane >> 4) << 2) + r;
      int tok = (nt << 4) + (lane & 15);
      float s = sc[nt][r] * ATTN_SCALE + brow[ql * 256 + tok];
      sc[nt][r] = s;
      m[r] = fmaxf(m[r], s);
    }
#pragma unroll
  for (int r = 0; r < 4; ++r) {
    m[r] = fmaxf(m[r], __shfl_xor(m[r], 1));
    m[r] = fmaxf(m[r], __shfl_xor(m[r], 2));
    m[r] = fmaxf(m[r], __shfl_xor(m[r], 4));
    m[r] = fmaxf(m[r], __shfl_xor(m[r], 8));
  }
  float l[4] = {0.f, 0.f, 0.f, 0.f};
#pragma unroll
  for (int nt = 0; nt < 16; ++nt)
#pragma unroll
    for (int r = 0; r < 4; ++r) {
      float p = __expf(sc[nt][r] - m[r]);
      sc[nt][r] = p;
      l[r] += p;
    }
#pragma unroll
  for (int r = 0; r < 4; ++r) {
    l[r] += __shfl_xor(l[r], 1);
    l[r] += __shfl_xor(l[r], 2);
    l[r] += __shfl_xor(l[r], 4);
    l[r] += __shfl_xor(l[r], 8);
    l[r] = 1.f / l[r];
  }
  __syncthreads();   // all waves done reading Qs/Ks before P overwrites them
#pragma unroll
  for (int nt = 0; nt < 16; ++nt)
#pragma unroll
    for (int r = 0; r < 4; ++r) {
      int prow = (wid << 4) + ((lane >> 4) << 2) + r;
      int tok = (nt << 4) + (lane & 15);
      *(unsigned short*)((char*)PKQ + swz512(prow, tok * 2)) = f2bf(sc[nt][r] * l[r]);
    }
  __syncthreads();
  // ---- O = P V ----
  f32x4 o[2]; o[0] = (f32x4)(0.f); o[1] = (f32x4)(0.f);
#pragma unroll
  for (int ktile = 0; ktile < 8; ++ktile) {
    int kb = (ktile << 6) + ((lane >> 4) << 4);
    int arow = (wid << 4) + (lane & 15);
    short8 a = *(const short8*)((char*)PKQ + swz512(arow, kb));
#pragma unroll
    for (int n2 = 0; n2 < 2; ++n2) {
      int vrow = (n2 << 4) + (lane & 15);
      short8 b = *(const short8*)((char*)Vt + swz512(vrow, kb));
      o[n2] = __builtin_amdgcn_mfma_f32_16x16x32_bf16(a, b, o[n2], 0, 0, 0);
    }
  }
#pragma unroll
  for (int n2 = 0; n2 < 2; ++n2)
#pragma unroll
    for (int r = 0; r < 4; ++r) {
      int q = qc * 64 + (wid << 4) + ((lane >> 4) << 2) + r;
      int dh = (n2 << 4) + (lane & 15);
      attnout[((size_t)win * NW + q) * CH + head * DH + dh] = f2bf(o[n2][r]);
    }
}

// ---------------- out-proj GEMM + bias + window-merge scatter ----------------
union SmemOP {
  struct { unsigned short A[8192], Bh[8192], Bl[8192]; } st;
  float ot[64][129];
};
__global__ __launch_bounds__(256) void k_outproj(const unsigned short* __restrict__ attnout,
                                                 const unsigned short* __restrict__ bhi,
                                                 const unsigned short* __restrict__ blo,
                                                 const float* __restrict__ bo,
                                                 float* __restrict__ out) {
  __shared__ SmemOP sm;
  int t = threadIdx.x;
  int mbase = blockIdx.x << 7, nbase = blockIdx.y << 7;
  int wid = t >> 6, lane = t & 63;
  int wm = wid >> 1, wn = wid & 1;
  f32x4 acc[4][4];
#pragma unroll
  for (int i = 0; i < 4; ++i)
#pragma unroll
    for (int j = 0; j < 4; ++j) acc[i][j] = (f32x4)(0.f);
  for (int kt = 0; kt < 4; ++kt) {
#pragma unroll
    for (int i = 0; i < 4; ++i) {
      int ch = t + (i << 8);
      int row = ch >> 3, c16 = ch & 7;
      size_t go = (size_t)(mbase + row) * 256 + (kt << 6) + (c16 << 3);
      short8 va = *(const short8*)(attnout + go);
      *(short8*)((char*)sm.st.A + swz128(row, c16 << 4)) = va;
      size_t gb = (size_t)(nbase + row) * 256 + (kt << 6) + (c16 << 3);
      short8 vh = *(const short8*)(bhi + gb);
      *(short8*)((char*)sm.st.Bh + swz128(row, c16 << 4)) = vh;
      short8 vl = *(const short8*)(blo + gb);
      *(short8*)((char*)sm.st.Bl + swz128(row, c16 << 4)) = vl;
    }
    __syncthreads();
#pragma unroll
    for (int kk = 0; kk < 2; ++kk) {
      int kb = (kk << 6) + ((lane >> 4) << 4);
      short8 a[4], bh[4], bl[4];
#pragma unroll
      for (int mi = 0; mi < 4; ++mi) {
        int row = (wm << 6) + (mi << 4) + (lane & 15);
        a[mi] = *(const short8*)((char*)sm.st.A + swz128(row, kb));
      }
#pragma unroll
      for (int ni = 0; ni < 4; ++ni) {
        int row = (wn << 6) + (ni << 4) + (lane & 15);
        bh[ni] = *(const short8*)((char*)sm.st.Bh + swz128(row, kb));
        bl[ni] = *(const short8*)((char*)sm.st.Bl + swz128(row, kb));
      }
#pragma unroll
      for (int mi = 0; mi < 4; ++mi)
#pragma unroll
        for (int ni = 0; ni < 4; ++ni) {
          acc[mi][ni] = __builtin_amdgcn_mfma_f32_16x16x32_bf16(a[mi], bh[ni], acc[mi][ni], 0, 0, 0);
          acc[mi][ni] = __builtin_amdgcn_mfma_f32_16x16x32_bf16(a[mi], bl[ni], acc[mi][ni], 0, 0, 0);
        }
    }
    __syncthreads();
  }
  // epilogue: restage f32 tile halves through LDS, scatter to (C,D,H,W)
  int win = mbase >> 8;
  int tokbase = mbase & 255;           // 0 or 128
  int gd = win >> 6, gh = (win >> 3) & 7, gw = win & 7;
  size_t posw = (size_t)gd * 4 * 4096 + (size_t)gh * 8 * 64 + (size_t)gw * 8;
  for (int half = 0; half < 2; ++half) {
    if (wm == half) {
#pragma unroll
      for (int mi = 0; mi < 4; ++mi)
#pragma unroll
        for (int ni = 0; ni < 4; ++ni)
#pragma unroll
          for (int r = 0; r < 4; ++r)
            sm.ot[(mi << 4) + ((lane >> 4) << 2) + r][(wn << 6) + (ni << 4) + (lane & 15)] = acc[mi][ni][r];
    }
    __syncthreads();
    int tok = tokbase + half * 64 + lane;
    int td = tok >> 6, th = (tok >> 3) & 7, tw = tok & 7;
    size_t pos = posw + (size_t)td * 4096 + (size_t)th * 64 + tw;
    for (int cc = 0; cc < 32; ++cc) {
      int c = (cc << 2) + wid;
      float v = sm.ot[lane][c] + bo[nbase + c];
      out[(size_t)(nbase + c) * 65536 + pos] = v;
    }
    __syncthreads();
  }
}

// ---------------- launch ----------------
extern "C" void kernel_launch(void* const* d_in, const int* in_sizes, int n_in,
                              void* d_out, int out_size, void* d_ws, size_t ws_size,
                              hipStream_t stream) {
  const float* x     = (const float*)d_in[0];
  const float* gamma = (const float*)d_in[1];
  const float* beta  = (const float*)d_in[2];
  const float* wqkv  = (const float*)d_in[3];
  const float* wout  = (const float*)d_in[4];
  const float* bout  = (const float*)d_in[5];
  const float* btab  = (const float*)d_in[6];
  const int*   ridx  = (const int*)d_in[7];
  float* out = (float*)d_out;
  char* ws = (char*)d_ws;
  // workspace layout (total ~137.4 MB; attnout aliases xn)
  unsigned short* xn   = (unsigned short*)(ws);                  // 33,554,432 B
  unsigned short* qkv  = (unsigned short*)(ws + 33554432);       // 100,663,296 B
  unsigned short* wqh  = (unsigned short*)(ws + 134217728);      // 393,216 B
  unsigned short* wql  = (unsigned short*)(ws + 134610944);      // 393,216 B
  unsigned short* woh  = (unsigned short*)(ws + 135004160);      // 131,072 B
  unsigned short* wol  = (unsigned short*)(ws + 135135232);      // 131,072 B
  float* bias8         = (float*)(ws + 135266304);               // 2,097,152 B
  unsigned short* attnout = xn;  // xn dead after k_qkv

  k_prepw<<<dim3(768), dim3(256), 0, stream>>>(wqkv, wout, wqh, wql, woh, wol);
  k_prepbias<<<dim3(2048), dim3(256), 0, stream>>>(btab, ridx, bias8);
  k_ln<<<dim3(1024), dim3(256), 0, stream>>>(x, gamma, beta, xn);
  k_qkv<<<dim3(512, 6), dim3(256), 0, stream>>>(xn, wqh, wql, qkv);
  k_attn<<<dim3(4, 8, 256), dim3(256), 0, stream>>>(qkv, bias8, attnout);
  k_outproj<<<dim3(512, 2), dim3(256), 0, stream>>>(attnout, woh, wol, bout, out);
}

// Round 4
// 240.130 us; speedup vs baseline: 1.1094x; 1.1094x over previous
//
#include <hip/hip_runtime.h>
#include <hip/hip_bf16.h>

// ---------------- types & helpers ----------------
typedef __attribute__((ext_vector_type(8))) short short8;
typedef __attribute__((ext_vector_type(4))) float f32x4;
typedef __attribute__((ext_vector_type(2))) unsigned int u32x2;

#define NWIN 256      // number of windows
#define NW   256      // tokens per window
#define CH   256      // channels
#define NH   8
#define DH   32
#define QKV_LD 768
#define ATTN_SCALE 0.17677669529663687f
#define LOG2E 1.4426950408889634f

__device__ __forceinline__ unsigned short f2bf(float f) {
  union { float f; unsigned u; } v; v.f = f;
  unsigned r = v.u + 0x7FFFu + ((v.u >> 16) & 1u);   // round-to-nearest-even
  return (unsigned short)(r >> 16);
}
__device__ __forceinline__ float bf2f(unsigned short h) {
  union { unsigned u; float f; } v; v.u = ((unsigned)h) << 16;
  return v.f;
}
__device__ __forceinline__ float bits2f(unsigned u) {
  union { unsigned u; float f; } v; v.u = u;
  return v.f;
}
// XOR swizzle: 128-byte rows (8 x 16B slots) -- T2 pattern
__device__ __forceinline__ int swz128(int row, int kb) { return row * 128 + (kb ^ ((row & 7) << 4)); }

// ---------------- weight prep: transpose + hi/lo bf16 split ----------------
__global__ __launch_bounds__(256) void k_prepw(const float* __restrict__ wqkv,
                                               const float* __restrict__ wout,
                                               unsigned short* __restrict__ wqh,
                                               unsigned short* __restrict__ wql,
                                               unsigned short* __restrict__ woh,
                                               unsigned short* __restrict__ wol) {
  int idx = blockIdx.x * 256 + threadIdx.x;       // 0..196607
  {
    int k = idx / 768, n = idx % 768;
    float v = wqkv[idx];
    unsigned short hi = f2bf(v);
    wqh[n * 256 + k] = hi;
    wql[n * 256 + k] = f2bf(v - bf2f(hi));
  }
  if (idx < 65536) {
    int k = idx >> 8, n = idx & 255;
    float v = wout[idx];
    unsigned short hi = f2bf(v);
    woh[n * 256 + k] = hi;
    wol[n * 256 + k] = f2bf(v - bf2f(hi));
  }
}

// ---------------- bias prep: bias2[h][q][k] = table[rel[q][k]][h] * log2(e) ----------------
__global__ __launch_bounds__(256) void k_prepbias(const float* __restrict__ table,
                                                  const int* __restrict__ relidx,
                                                  float* __restrict__ bias2) {
  int idx = blockIdx.x * 256 + threadIdx.x;       // 0..524287
  int h = idx >> 16;
  int qk = idx & 65535;
  bias2[idx] = table[relidx[qk] * 8 + h] * LOG2E;
}

// ---------------- LN + window gather: x (C,D,H,W) f32 -> xn [win][tok][c] bf16 ----------------
__global__ __launch_bounds__(256) void k_ln(const float* __restrict__ x,
                                            const float* __restrict__ gamma,
                                            const float* __restrict__ beta,
                                            unsigned short* __restrict__ xn) {
  __shared__ unsigned short buf[256][66];
  __shared__ float stats[2][4][64];
  int bid = blockIdx.x;
  int d = bid >> 6, h = bid & 63;
  int t = threadIdx.x;
  int w = t & 63, cq = t >> 6;
  const float* xrow = x + (size_t)d * 4096 + (size_t)h * 64;
  float s0 = 0.f, s1 = 0.f;
  for (int ci = 0; ci < 64; ++ci) {
    int c = ci * 4 + cq;
    float v = xrow[(size_t)c * 65536 + w];
    buf[c][w] = f2bf(v);
    s0 += v; s1 += v * v;
  }
  stats[0][cq][w] = s0; stats[1][cq][w] = s1;
  __syncthreads();
  int lane = t & 63, wv = t >> 6;
  int winb = (d >> 2) * 64 + (h >> 3) * 8;
  int tokb = (d & 3) * 64 + (h & 7) * 8;
  for (int wi = 0; wi < 16; ++wi) {
    int w2 = wi * 4 + wv;
    float sum = stats[0][0][w2] + stats[0][1][w2] + stats[0][2][w2] + stats[0][3][w2];
    float sq  = stats[1][0][w2] + stats[1][1][w2] + stats[1][2][w2] + stats[1][3][w2];
    float mu = sum * 0.00390625f;
    float var = sq * 0.00390625f - mu * mu;
    float rstd = rsqrtf(var + 1e-5f);
    int win = winb + (w2 >> 3);
    int tok = tokb + (w2 & 7);
    unsigned short* dst = xn + ((size_t)win * NW + tok) * CH;
    for (int cc = 0; cc < 4; ++cc) {
      int c = cc * 64 + lane;
      float v = bf2f(buf[c][w2]);
      dst[c] = f2bf((v - mu) * rstd * gamma[c] + beta[c]);
    }
  }
}

// ---------------- QKV GEMM ----------------
__global__ __launch_bounds__(256) void k_qkv(const unsigned short* __restrict__ xn,
                                             const unsigned short* __restrict__ bhi,
                                             const unsigned short* __restrict__ blo,
                                             unsigned short* __restrict__ qkv) {
  __shared__ unsigned short sA[8192], sBh[8192], sBl[8192];
  int t = threadIdx.x;
  int mbase = blockIdx.x << 7, nbase = blockIdx.y << 7;
  int wid = t >> 6, lane = t & 63;
  int wm = wid >> 1, wn = wid & 1;
  f32x4 acc[4][4];
#pragma unroll
  for (int i = 0; i < 4; ++i)
#pragma unroll
    for (int j = 0; j < 4; ++j) acc[i][j] = (f32x4)(0.f);
  for (int kt = 0; kt < 4; ++kt) {
#pragma unroll
    for (int i = 0; i < 4; ++i) {
      int ch = t + (i << 8);
      int row = ch >> 3, c16 = ch & 7;
      size_t go = (size_t)(mbase + row) * 256 + (kt << 6) + (c16 << 3);
      short8 va = *(const short8*)(xn + go);
      *(short8*)((char*)sA + swz128(row, c16 << 4)) = va;
      size_t gb = (size_t)(nbase + row) * 256 + (kt << 6) + (c16 << 3);
      short8 vh = *(const short8*)(bhi + gb);
      *(short8*)((char*)sBh + swz128(row, c16 << 4)) = vh;
      short8 vl = *(const short8*)(blo + gb);
      *(short8*)((char*)sBl + swz128(row, c16 << 4)) = vl;
    }
    __syncthreads();
#pragma unroll
    for (int kk = 0; kk < 2; ++kk) {
      int kb = (kk << 6) + ((lane >> 4) << 4);
      short8 a[4], bh[4], bl[4];
#pragma unroll
      for (int mi = 0; mi < 4; ++mi) {
        int row = (wm << 6) + (mi << 4) + (lane & 15);
        a[mi] = *(const short8*)((char*)sA + swz128(row, kb));
      }
#pragma unroll
      for (int ni = 0; ni < 4; ++ni) {
        int row = (wn << 6) + (ni << 4) + (lane & 15);
        bh[ni] = *(const short8*)((char*)sBh + swz128(row, kb));
        bl[ni] = *(const short8*)((char*)sBl + swz128(row, kb));
      }
#pragma unroll
      for (int mi = 0; mi < 4; ++mi)
#pragma unroll
        for (int ni = 0; ni < 4; ++ni) {
          acc[mi][ni] = __builtin_amdgcn_mfma_f32_16x16x32_bf16(a[mi], bh[ni], acc[mi][ni], 0, 0, 0);
          acc[mi][ni] = __builtin_amdgcn_mfma_f32_16x16x32_bf16(a[mi], bl[ni], acc[mi][ni], 0, 0, 0);
        }
    }
    __syncthreads();
  }
#pragma unroll
  for (int mi = 0; mi < 4; ++mi)
#pragma unroll
    for (int ni = 0; ni < 4; ++ni)
#pragma unroll
      for (int r = 0; r < 4; ++r) {
        int m = mbase + (wm << 6) + (mi << 4) + ((lane >> 4) << 2) + r;
        int n = nbase + (wn << 6) + (ni << 4) + (lane & 15);
        qkv[(size_t)m * QKV_LD + n] = f2bf(acc[mi][ni][r]);
      }
}

// ---------------- attention v4: v3 + FIXED bias q-offset (wid*64 was missing) ----------------
__global__ __launch_bounds__(256) void k_attn(const unsigned short* __restrict__ qkv,
                                              const float* __restrict__ bias2,
                                              unsigned short* __restrict__ attnout) {
  __shared__ unsigned short Vt[8192];      // [32 dh][256 tok] swizzled 512B rows = 16KB
  __shared__ unsigned short Pb[4][4096];   // per-wave [64 q][64 tok] bf16, 128B rows swizzled
  int win = blockIdx.x, head = blockIdx.y;
  int t = threadIdx.x, wid = t >> 6, lane = t & 63;
  int l15 = lane & 15, g = lane >> 4;
  int sw = (l15 & 7) << 4;
  const unsigned short* base = qkv + (size_t)win * NW * QKV_LD + head * DH;
  const float SCALE2 = ATTN_SCALE * LOG2E;

  { // stage V transposed: thread t handles V row tok=t
    const unsigned short* vrow = base + 2 * CH + (size_t)t * QKV_LD;
    short8 v0 = *(const short8*)(vrow);
    short8 v1 = *(const short8*)(vrow + 8);
    short8 v2 = *(const short8*)(vrow + 16);
    short8 v3 = *(const short8*)(vrow + 24);
    int tb = t * 2;
#pragma unroll
    for (int j = 0; j < 8; ++j) {
      int sj = tb ^ ((j & 7) << 4);
      *(unsigned short*)((char*)Vt + (j)      * 512 + sj) = (unsigned short)v0[j];
      *(unsigned short*)((char*)Vt + (8 + j)  * 512 + sj) = (unsigned short)v1[j];
      *(unsigned short*)((char*)Vt + (16 + j) * 512 + sj) = (unsigned short)v2[j];
      *(unsigned short*)((char*)Vt + (24 + j) * 512 + sj) = (unsigned short)v3[j];
    }
  }
  short8 bq[4];
#pragma unroll
  for (int qt = 0; qt < 4; ++qt)
    bq[qt] = *(const short8*)(base + (size_t)(wid * 64 + qt * 16 + l15) * QKV_LD + g * 8);

  f32x4 o[4][2];
#pragma unroll
  for (int qt = 0; qt < 4; ++qt) { o[qt][0] = (f32x4)(0.f); o[qt][1] = (f32x4)(0.f); }
  float m_[4] = {-1e30f, -1e30f, -1e30f, -1e30f};
  float l_[4] = {0.f, 0.f, 0.f, 0.f};
  const f32x4 zero = (f32x4)(0.f);
  char* Pw = (char*)Pb[wid];
  const float* bb = bias2 + ((size_t)head << 16);

  __syncthreads();

  for (int ck = 0; ck < 4; ++ck) {
    short8 ak[4];
#pragma unroll
    for (int tt = 0; tt < 4; ++tt)
      ak[tt] = *(const short8*)(base + (size_t)(ck * 64 + tt * 16 + l15) * QKV_LD + CH + g * 8);
    f32x4 z[4][4];
#pragma unroll
    for (int tt = 0; tt < 4; ++tt)
#pragma unroll
      for (int qt = 0; qt < 4; ++qt)
        z[tt][qt] = __builtin_amdgcn_mfma_f32_16x16x32_bf16(ak[tt], bq[qt], zero, 0, 0, 0);
    float zm[4] = {-1e30f, -1e30f, -1e30f, -1e30f};
#pragma unroll
    for (int qt = 0; qt < 4; ++qt) {
      // FIX: global q row = wid*64 + qt*16 + l15 (wid*64 was missing in v2/v3)
      const float* bp = bb + (size_t)(wid * 64 + qt * 16 + l15) * 256 + ck * 64 + g * 4;
#pragma unroll
      for (int tt = 0; tt < 4; ++tt) {
        f32x4 b4 = *(const f32x4*)(bp + tt * 16);
#pragma unroll
        for (int r = 0; r < 4; ++r) {
          float zz = fmaf(z[tt][qt][r], SCALE2, b4[r]);
          z[tt][qt][r] = zz;
          zm[qt] = fmaxf(zm[qt], zz);
        }
      }
    }
    // exact running max: reduce across g, always rescale
#pragma unroll
    for (int qt = 0; qt < 4; ++qt) {
      zm[qt] = fmaxf(zm[qt], __shfl_xor(zm[qt], 16));
      zm[qt] = fmaxf(zm[qt], __shfl_xor(zm[qt], 32));
      float mn = fmaxf(m_[qt], zm[qt]);
      float al = __builtin_amdgcn_exp2f(m_[qt] - mn);   // 0 on first chunk
      m_[qt] = mn;
      l_[qt] *= al;
#pragma unroll
      for (int r = 0; r < 4; ++r) {
        float ar = __shfl(al, g * 4 + r);
        o[qt][0][r] *= ar;
        o[qt][1][r] *= ar;
      }
    }
    // P = exp2(z - m) -> bf16; l accumulates the ROUNDED values (consistency)
#pragma unroll
    for (int qt = 0; qt < 4; ++qt) {
      int row = qt * 16 + l15;
#pragma unroll
      for (int tt = 0; tt < 4; ++tt) {
        float p0 = __builtin_amdgcn_exp2f(z[tt][qt][0] - m_[qt]);
        float p1 = __builtin_amdgcn_exp2f(z[tt][qt][1] - m_[qt]);
        float p2 = __builtin_amdgcn_exp2f(z[tt][qt][2] - m_[qt]);
        float p3 = __builtin_amdgcn_exp2f(z[tt][qt][3] - m_[qt]);
        __hip_bfloat162 lo = __float22bfloat162_rn(float2{p0, p1});
        __hip_bfloat162 hi = __float22bfloat162_rn(float2{p2, p3});
        u32x2 pk;
        pk.x = *(unsigned int*)&lo;
        pk.y = *(unsigned int*)&hi;
        float p0r = bits2f(pk.x << 16);
        float p1r = bits2f(pk.x & 0xFFFF0000u);
        float p2r = bits2f(pk.y << 16);
        float p3r = bits2f(pk.y & 0xFFFF0000u);
        l_[qt] += (p0r + p1r) + (p2r + p3r);
        *(u32x2*)(Pw + row * 128 + ((tt * 32 + g * 8) ^ sw)) = pk;
      }
    }
#pragma unroll
    for (int s = 0; s < 2; ++s) {
      short8 pa[4], vb[2];
#pragma unroll
      for (int qt = 0; qt < 4; ++qt)
        pa[qt] = *(const short8*)(Pw + (qt * 16 + l15) * 128 + ((s * 64 + g * 16) ^ sw));
#pragma unroll
      for (int dht = 0; dht < 2; ++dht)
        vb[dht] = *(const short8*)((char*)Vt + (dht * 16 + l15) * 512 + ((ck * 128 + s * 64 + g * 16) ^ sw));
#pragma unroll
      for (int qt = 0; qt < 4; ++qt)
#pragma unroll
        for (int dht = 0; dht < 2; ++dht)
          o[qt][dht] = __builtin_amdgcn_mfma_f32_16x16x32_bf16(pa[qt], vb[dht], o[qt][dht], 0, 0, 0);
    }
  }
#pragma unroll
  for (int qt = 0; qt < 4; ++qt) {
    float lq = l_[qt];
    lq += __shfl_xor(lq, 16);
    lq += __shfl_xor(lq, 32);
    float linv = 1.0f / lq;
#pragma unroll
    for (int r = 0; r < 4; ++r) {
      float lr = __shfl(linv, g * 4 + r);
      int q = wid * 64 + qt * 16 + g * 4 + r;
      unsigned short* dst = attnout + ((size_t)(win * NW + q)) * CH + head * DH + l15;
      dst[0]  = f2bf(o[qt][0][r] * lr);
      dst[16] = f2bf(o[qt][1][r] * lr);
    }
  }
}

// ---------------- out-proj GEMM + bias + window-merge scatter ----------------
union SmemOP {
  struct { unsigned short A[8192], Bh[8192], Bl[8192]; } st;
  float ot[64][129];
};
__global__ __launch_bounds__(256) void k_outproj(const unsigned short* __restrict__ attnout,
                                                 const unsigned short* __restrict__ bhi,
                                                 const unsigned short* __restrict__ blo,
                                                 const float* __restrict__ bo,
                                                 float* __restrict__ out) {
  __shared__ SmemOP sm;
  int t = threadIdx.x;
  int mbase = blockIdx.x << 7, nbase = blockIdx.y << 7;
  int wid = t >> 6, lane = t & 63;
  int wm = wid >> 1, wn = wid & 1;
  f32x4 acc[4][4];
#pragma unroll
  for (int i = 0; i < 4; ++i)
#pragma unroll
    for (int j = 0; j < 4; ++j) acc[i][j] = (f32x4)(0.f);
  for (int kt = 0; kt < 4; ++kt) {
#pragma unroll
    for (int i = 0; i < 4; ++i) {
      int ch = t + (i << 8);
      int row = ch >> 3, c16 = ch & 7;
      size_t go = (size_t)(mbase + row) * 256 + (kt << 6) + (c16 << 3);
      short8 va = *(const short8*)(attnout + go);
      *(short8*)((char*)sm.st.A + swz128(row, c16 << 4)) = va;
      size_t gb = (size_t)(nbase + row) * 256 + (kt << 6) + (c16 << 3);
      short8 vh = *(const short8*)(bhi + gb);
      *(short8*)((char*)sm.st.Bh + swz128(row, c16 << 4)) = vh;
      short8 vl = *(const short8*)(blo + gb);
      *(short8*)((char*)sm.st.Bl + swz128(row, c16 << 4)) = vl;
    }
    __syncthreads();
#pragma unroll
    for (int kk = 0; kk < 2; ++kk) {
      int kb = (kk << 6) + ((lane >> 4) << 4);
      short8 a[4], bh[4], bl[4];
#pragma unroll
      for (int mi = 0; mi < 4; ++mi) {
        int row = (wm << 6) + (mi << 4) + (lane & 15);
        a[mi] = *(const short8*)((char*)sm.st.A + swz128(row, kb));
      }
#pragma unroll
      for (int ni = 0; ni < 4; ++ni) {
        int row = (wn << 6) + (ni << 4) + (lane & 15);
        bh[ni] = *(const short8*)((char*)sm.st.Bh + swz128(row, kb));
        bl[ni] = *(const short8*)((char*)sm.st.Bl + swz128(row, kb));
      }
#pragma unroll
      for (int mi = 0; mi < 4; ++mi)
#pragma unroll
        for (int ni = 0; ni < 4; ++ni) {
          acc[mi][ni] = __builtin_amdgcn_mfma_f32_16x16x32_bf16(a[mi], bh[ni], acc[mi][ni], 0, 0, 0);
          acc[mi][ni] = __builtin_amdgcn_mfma_f32_16x16x32_bf16(a[mi], bl[ni], acc[mi][ni], 0, 0, 0);
        }
    }
    __syncthreads();
  }
  int win = mbase >> 8;
  int tokbase = mbase & 255;
  int gd = win >> 6, gh = (win >> 3) & 7, gw = win & 7;
  size_t posw = (size_t)gd * 4 * 4096 + (size_t)gh * 8 * 64 + (size_t)gw * 8;
  for (int half = 0; half < 2; ++half) {
    if (wm == half) {
#pragma unroll
      for (int mi = 0; mi < 4; ++mi)
#pragma unroll
        for (int ni = 0; ni < 4; ++ni)
#pragma unroll
          for (int r = 0; r < 4; ++r)
            sm.ot[(mi << 4) + ((lane >> 4) << 2) + r][(wn << 6) + (ni << 4) + (lane & 15)] = acc[mi][ni][r];
    }
    __syncthreads();
    int tok = tokbase + half * 64 + lane;
    int td = tok >> 6, th = (tok >> 3) & 7, tw = tok & 7;
    size_t pos = posw + (size_t)td * 4096 + (size_t)th * 64 + tw;
    for (int cc = 0; cc < 32; ++cc) {
      int c = (cc << 2) + wid;
      float v = sm.ot[lane][c] + bo[nbase + c];
      out[(size_t)(nbase + c) * 65536 + pos] = v;
    }
    __syncthreads();
  }
}

// ---------------- launch ----------------
extern "C" void kernel_launch(void* const* d_in, const int* in_sizes, int n_in,
                              void* d_out, int out_size, void* d_ws, size_t ws_size,
                              hipStream_t stream) {
  const float* x     = (const float*)d_in[0];
  const float* gamma = (const float*)d_in[1];
  const float* beta  = (const float*)d_in[2];
  const float* wqkv  = (const float*)d_in[3];
  const float* wout  = (const float*)d_in[4];
  const float* bout  = (const float*)d_in[5];
  const float* btab  = (const float*)d_in[6];
  const int*   ridx  = (const int*)d_in[7];
  float* out = (float*)d_out;
  char* ws = (char*)d_ws;
  unsigned short* xn   = (unsigned short*)(ws);                  // 33,554,432 B
  unsigned short* qkv  = (unsigned short*)(ws + 33554432);       // 100,663,296 B
  unsigned short* wqh  = (unsigned short*)(ws + 134217728);
  unsigned short* wql  = (unsigned short*)(ws + 134610944);
  unsigned short* woh  = (unsigned short*)(ws + 135004160);
  unsigned short* wol  = (unsigned short*)(ws + 135135232);
  float* bias2         = (float*)(ws + 135266304);
  unsigned short* attnout = xn;  // xn dead after k_qkv

  k_prepw<<<dim3(768), dim3(256), 0, stream>>>(wqkv, wout, wqh, wql, woh, wol);
  k_prepbias<<<dim3(2048), dim3(256), 0, stream>>>(btab, ridx, bias2);
  k_ln<<<dim3(1024), dim3(256), 0, stream>>>(x, gamma, beta, xn);
  k_qkv<<<dim3(512, 6), dim3(256), 0, stream>>>(xn, wqh, wql, qkv);
  k_attn<<<dim3(256, 8), dim3(256), 0, stream>>>(qkv, bias2, attnout);
  k_outproj<<<dim3(512, 2), dim3(256), 0, stream>>>(attnout, woh, wol, bout, out);
}